// Round 1
// baseline (610.104 us; speedup 1.0000x reference)
//
#include <hip/hip_runtime.h>
#include <cstdint>
#include <cstddef>

// Problem constants (fixed by the reference): B=4, S=2048, IN=4096, OUT=4096
// GEMM: M=8192, N=4096, K=4096.  A [M,K] fp32 -> bf16 ws; W [N,K] int32 ->
// dequant bf16 ws; C [M,N] fp32 = A·W^T + bias.

#define BM 128
#define BN 128
#define BK 32

typedef __bf16 bf16x8 __attribute__((ext_vector_type(8)));
typedef float floatx4 __attribute__((ext_vector_type(4)));
typedef float float4v __attribute__((ext_vector_type(4)));
typedef int int4v __attribute__((ext_vector_type(4)));
typedef unsigned short ushort8v __attribute__((ext_vector_type(8)));
typedef unsigned short ushort4v __attribute__((ext_vector_type(4)));

#define AS1 __attribute__((address_space(1)))
#define AS3 __attribute__((address_space(3)))

// Async global->LDS, 16B per lane. LDS dest is wave-uniform base + lane*16
// (hardware constraint, m104/m108) — our flat staging layout respects this.
// AS casts go through integers: generic->AS1 is bit-identical; generic->AS3
// truncates to the low 32 bits, which on gfx9+ equal the LDS offset.
__device__ __forceinline__ void load16_g2l(const void* g, void* l) {
    __builtin_amdgcn_global_load_lds((const AS1 void*)(uintptr_t)g,
                                     (AS3 void*)(uint32_t)(uintptr_t)l,
                                     16, 0, 0);
}

// fp32 -> bf16 round-to-nearest-even (bit-level; avoids header API drift)
__device__ __forceinline__ unsigned short f2bf(float f) {
    union { float f; uint32_t u; } v; v.f = f;
    uint32_t u = v.u;
    uint32_t r = (u + 0x7fffu + ((u >> 16) & 1u)) >> 16;
    return (unsigned short)r;
}

// ---------------- pre-pass 1: A fp32 -> bf16 ----------------
__global__ __launch_bounds__(256) void cvt_f32_bf16(
    const float* __restrict__ in, unsigned short* __restrict__ out, int n) {
    int i = (blockIdx.x * 256 + threadIdx.x) * 8;
    if (i + 8 > n) {
        for (; i < n; ++i) out[i] = f2bf(in[i]);
        return;
    }
    float4v f0 = *(const float4v*)(in + i);
    float4v f1 = *(const float4v*)(in + i + 4);
    ushort8v r;
    r[0] = f2bf(f0[0]); r[1] = f2bf(f0[1]); r[2] = f2bf(f0[2]); r[3] = f2bf(f0[3]);
    r[4] = f2bf(f1[0]); r[5] = f2bf(f1[1]); r[6] = f2bf(f1[2]); r[7] = f2bf(f1[3]);
    *(ushort8v*)(out + i) = r;
}

// ---------------- pre-pass 2: W int32 -> dequant bf16 ----------------
// one block per output row; (w - zp[row]) * scale[row]
__global__ __launch_bounds__(256) void dequant_w(
    const int* __restrict__ w, const float* __restrict__ scale,
    const float* __restrict__ zp, unsigned short* __restrict__ out, int K) {
    const int row = blockIdx.x;
    const float s = scale[row];
    const float z = zp[row];
    const size_t base = (size_t)row * K;
    for (int c = threadIdx.x * 4; c < K; c += 256 * 4) {
        int4v wv = *(const int4v*)(w + base + c);
        ushort4v o;
        o[0] = f2bf(((float)wv[0] - z) * s);
        o[1] = f2bf(((float)wv[1] - z) * s);
        o[2] = f2bf(((float)wv[2] - z) * s);
        o[3] = f2bf(((float)wv[3] - z) * s);
        *(ushort4v*)(out + base + c) = o;
    }
}

// ---------------- main GEMM: bf16 B^T, m97 structure ----------------
// 128x128 tile, BK=32, 256 threads = 4 waves in 2x2; each wave owns 64x64 =
// 4x4 grid of 16x16x32 MFMA tiles. global_load_lds width-16 staging into
// contiguous [row][k] LDS tiles (no padding — wave-uniform base rule).
__global__ __launch_bounds__(256) void gemm_bf16_bt(
    const unsigned short* __restrict__ A,  // [M,K] bf16 bits
    const unsigned short* __restrict__ B,  // [N,K] bf16 bits (W^T layout)
    const float* __restrict__ bias,        // [N]
    float* __restrict__ C,                 // [M,N] fp32
    int M, int N, int K) {
    __shared__ unsigned short lds_a[BM * BK];  // 8 KB
    __shared__ unsigned short lds_b[BN * BK];  // 8 KB

    const int tid = threadIdx.x;
    const int lane = tid & 63;
    const int wave = tid >> 6;

    const int n0 = blockIdx.x * BN;
    const int m0 = blockIdx.y * BM;

    const int wm = (wave >> 1) * 64;  // wave's m offset within tile
    const int wn = (wave & 1) * 64;   // wave's n offset within tile

    floatx4 acc[4][4];
    const floatx4 zero = {0.f, 0.f, 0.f, 0.f};
#pragma unroll
    for (int i = 0; i < 4; ++i)
#pragma unroll
        for (int j = 0; j < 4; ++j) acc[i][j] = zero;

    // Staging: 128 rows x 32 k-elems (64 B/row = 4 lane-loads of 16 B).
    // flat index fl in [0,512): row = fl>>2, k-chunk = (fl&3)*8 elements.
    // Two issues per thread per matrix: fl = tid and tid+256.
    const int fl0 = tid, fl1 = tid + 256;
    const int row0 = fl0 >> 2, row1 = fl1 >> 2;
    const int kc0 = (fl0 & 3) * 8, kc1 = (fl1 & 3) * 8;

    const unsigned short* ga0 = A + (size_t)(m0 + row0) * K + kc0;
    const unsigned short* ga1 = A + (size_t)(m0 + row1) * K + kc1;
    const unsigned short* gb0 = B + (size_t)(n0 + row0) * K + kc0;
    const unsigned short* gb1 = B + (size_t)(n0 + row1) * K + kc1;

    unsigned short* la0 = &lds_a[fl0 * 8];
    unsigned short* la1 = &lds_a[fl1 * 8];
    unsigned short* lb0 = &lds_b[fl0 * 8];
    unsigned short* lb1 = &lds_b[fl1 * 8];

    // MFMA fragment addressing (16x16x32 bf16):
    //   A operand: lane holds A[m = lane&15][k = (lane>>4)*8 .. +8)
    //   B operand: lane holds Bt[n = lane&15][k = (lane>>4)*8 .. +8)
    const int fm = lane & 15;
    const int fq = lane >> 4;

    const unsigned short* ra[4];
    const unsigned short* rb[4];
#pragma unroll
    for (int t = 0; t < 4; ++t) {
        ra[t] = &lds_a[(wm + t * 16 + fm) * BK + fq * 8];
        rb[t] = &lds_b[(wn + t * 16 + fm) * BK + fq * 8];
    }

    for (int k0 = 0; k0 < K; k0 += BK) {
        __syncthreads();  // prior iteration's LDS reads complete
        load16_g2l(ga0 + k0, la0);
        load16_g2l(ga1 + k0, la1);
        load16_g2l(gb0 + k0, lb0);
        load16_g2l(gb1 + k0, lb1);
        __syncthreads();  // staging drained (vmcnt(0) before s_barrier)

        bf16x8 av[4], bv[4];
#pragma unroll
        for (int t = 0; t < 4; ++t) av[t] = *(const bf16x8*)ra[t];
#pragma unroll
        for (int t = 0; t < 4; ++t) bv[t] = *(const bf16x8*)rb[t];
#pragma unroll
        for (int i = 0; i < 4; ++i)
#pragma unroll
            for (int j = 0; j < 4; ++j)
                acc[i][j] = __builtin_amdgcn_mfma_f32_16x16x32_bf16(
                    av[i], bv[j], acc[i][j], 0, 0, 0);
    }

    // Epilogue. C/D layout (m89-verified): col = lane&15 (n), row = (lane>>4)*4
    // + reg (m). Fuse bias.
#pragma unroll
    for (int j = 0; j < 4; ++j) {
        const int col = n0 + wn + j * 16 + fm;
        const float bvl = bias[col];
#pragma unroll
        for (int i = 0; i < 4; ++i) {
            const int rbase = m0 + wm + i * 16 + fq * 4;
#pragma unroll
            for (int r = 0; r < 4; ++r) {
                C[(size_t)(rbase + r) * N + col] = acc[i][j][r] + bvl;
            }
        }
    }
}

// ---------------- fallback (only if ws too small): naive fp32 ----------------
__global__ __launch_bounds__(256) void fallback_naive(
    const float* __restrict__ in, const int* __restrict__ w,
    const float* __restrict__ scale, const float* __restrict__ zp,
    const float* __restrict__ bias, float* __restrict__ out,
    int M, int N, int K) {
    int idx = blockIdx.x * 256 + threadIdx.x;
    if (idx >= M * N) return;
    int m = idx / N, n = idx - m * N;
    const float s = scale[n], z = zp[n];
    const float* a = in + (size_t)m * K;
    const int* wr = w + (size_t)n * K;
    float acc = 0.f;
    for (int k = 0; k < K; ++k) acc += a[k] * ((float)wr[k] - z);
    out[idx] = acc * s + bias[n];
}

extern "C" void kernel_launch(void* const* d_in, const int* in_sizes, int n_in,
                              void* d_out, int out_size, void* d_ws, size_t ws_size,
                              hipStream_t stream) {
    constexpr int M = 4 * 2048;  // B*S = 8192
    constexpr int K = 4096;      // IN
    constexpr int N = 4096;      // OUT

    const float* input = (const float*)d_in[0];
    const int* w8 = (const int*)d_in[1];
    const float* scale = (const float*)d_in[2];
    const float* zp = (const float*)d_in[3];
    const float* bias = (const float*)d_in[4];
    float* out = (float*)d_out;

    const size_t need = ((size_t)M * K + (size_t)N * K) * sizeof(unsigned short);
    if (ws_size < need) {
        const int total = M * N;
        fallback_naive<<<(total + 255) / 256, 256, 0, stream>>>(
            input, w8, scale, zp, bias, out, M, N, K);
        return;
    }

    unsigned short* wsA = (unsigned short*)d_ws;           // M*K bf16
    unsigned short* wsW = wsA + (size_t)M * K;             // N*K bf16

    const int nA = M * K;  // 33,554,432 — divisible by 2048
    cvt_f32_bf16<<<nA / (256 * 8), 256, 0, stream>>>(input, wsA, nA);
    dequant_w<<<N, 256, 0, stream>>>(w8, scale, zp, wsW, K);

    dim3 grid(N / BN, M / BM);  // (32, 64) = 2048 blocks
    gemm_bf16_bt<<<grid, 256, 0, stream>>>(wsA, wsW, bias, out, M, N, K);
}

// Round 2
// 589.285 us; speedup vs baseline: 1.0353x; 1.0353x over previous
//
#include <hip/hip_runtime.h>
#include <cstdint>
#include <cstddef>

// B=4, S=2048, IN=4096, OUT=4096 -> GEMM M=8192, N=4096, K=4096.
// A [M,K] fp32 -> bf16 ws; W [N,K] int32 -> dequant bf16 ws;
// C [M,N] fp32 = A·W^T + bias.

#define BM 128
#define BN 128
#define BK 32

typedef __bf16 bf16x8 __attribute__((ext_vector_type(8)));
typedef float floatx4 __attribute__((ext_vector_type(4)));
typedef float float4v __attribute__((ext_vector_type(4)));
typedef int int4v __attribute__((ext_vector_type(4)));
typedef unsigned short ushort8v __attribute__((ext_vector_type(8)));
typedef unsigned short ushort4v __attribute__((ext_vector_type(4)));

#define AS1 __attribute__((address_space(1)))
#define AS3 __attribute__((address_space(3)))

// Async global->LDS, 16B/lane. LDS dest = wave-uniform base + lane*16
// (m104/m108) — so the SWIZZLE lives on the global source address, not the
// LDS destination.
__device__ __forceinline__ void load16_g2l(const void* g, void* l) {
    __builtin_amdgcn_global_load_lds((const AS1 void*)(uintptr_t)g,
                                     (AS3 void*)(uint32_t)(uintptr_t)l,
                                     16, 0, 0);
}

// fp32 -> bf16 round-to-nearest-even (bit-level)
__device__ __forceinline__ unsigned short f2bf(float f) {
    union { float f; uint32_t u; } v; v.f = f;
    uint32_t u = v.u;
    uint32_t r = (u + 0x7fffu + ((u >> 16) & 1u)) >> 16;
    return (unsigned short)r;
}

// ---------------- fused pre-pass ----------------
// blocks [0, GA): A fp32->bf16, 1024 elems/block (16B/lane reads, 8B writes)
// blocks [GA, GA+GW): W int32->dequant bf16, flat 1024 elems/block; a 4-elem
// group never crosses a row (4096 % 4 == 0), row = idx >> 12.
__global__ __launch_bounds__(256) void prep(
    const float* __restrict__ a_in, unsigned short* __restrict__ a_out,
    const int* __restrict__ w, const float* __restrict__ scale,
    const float* __restrict__ zp, unsigned short* __restrict__ w_out,
    int ga_blocks) {
    const int bid = blockIdx.x;
    if (bid < ga_blocks) {
        const size_t i = ((size_t)bid * 256 + threadIdx.x) * 4;
        float4v f = *(const float4v*)(a_in + i);
        ushort4v r;
        r[0] = f2bf(f[0]); r[1] = f2bf(f[1]); r[2] = f2bf(f[2]); r[3] = f2bf(f[3]);
        *(ushort4v*)(a_out + i) = r;
    } else {
        const size_t i = ((size_t)(bid - ga_blocks) * 256 + threadIdx.x) * 4;
        const int row = (int)(i >> 12);  // K = 4096
        const float s = scale[row];
        const float z = zp[row];
        int4v wv = *(const int4v*)(w + i);
        ushort4v o;
        o[0] = f2bf(((float)wv[0] - z) * s);
        o[1] = f2bf(((float)wv[1] - z) * s);
        o[2] = f2bf(((float)wv[2] - z) * s);
        o[3] = f2bf(((float)wv[3] - z) * s);
        *(ushort4v*)(w_out + i) = o;
    }
}

// ---------------- main GEMM: bf16 B^T, m97 structure + XOR swizzle ----------
// 128x128 tile, BK=32, 4 waves in 2x2, wave = 4x4 of 16x16x32 bf16 MFMA.
// LDS tile = 512 chunks of 16B. Logical (row r, chunk c) stored at physical
// slot p = r*4 + (c ^ ((r>>1)&3)). Fragment reads then hit each bank-quad
// exactly twice per quarter-wave phase (2-way = free, m136) instead of 8-way.
__global__ __launch_bounds__(256) void gemm_bf16_bt(
    const unsigned short* __restrict__ A,  // [M,K] bf16 bits
    const unsigned short* __restrict__ B,  // [N,K] bf16 bits (W^T layout)
    const float* __restrict__ bias,        // [N]
    float* __restrict__ C,                 // [M,N] fp32
    int M, int N, int K) {
    __shared__ unsigned short lds_a[BM * BK];  // 8 KB
    __shared__ unsigned short lds_b[BN * BK];  // 8 KB

    const int tid = threadIdx.x;
    const int lane = tid & 63;
    const int wave = tid >> 6;

    const int n0 = blockIdx.x * BN;
    const int m0 = blockIdx.y * BM;

    const int wm = (wave >> 1) * 64;
    const int wn = (wave & 1) * 64;

    floatx4 acc[4][4];
    const floatx4 zero = {0.f, 0.f, 0.f, 0.f};
#pragma unroll
    for (int i = 0; i < 4; ++i)
#pragma unroll
        for (int j = 0; j < 4; ++j) acc[i][j] = zero;

    // Staging: physical slot fl holds global (row = fl>>2,
    // chunk = (fl&3) ^ ((row>>1)&3)).  Two issues/thread/matrix.
    const int fl0 = tid, fl1 = tid + 256;
    const int row0 = fl0 >> 2, row1 = fl1 >> 2;
    const int kc0 = (((fl0 & 3) ^ ((row0 >> 1) & 3)) * 8);
    const int kc1 = (((fl1 & 3) ^ ((row1 >> 1) & 3)) * 8);

    const unsigned short* ga0 = A + (size_t)(m0 + row0) * K + kc0;
    const unsigned short* ga1 = A + (size_t)(m0 + row1) * K + kc1;
    const unsigned short* gb0 = B + (size_t)(n0 + row0) * K + kc0;
    const unsigned short* gb1 = B + (size_t)(n0 + row1) * K + kc1;

    unsigned short* la0 = &lds_a[fl0 * 8];
    unsigned short* la1 = &lds_a[fl1 * 8];
    unsigned short* lb0 = &lds_b[fl0 * 8];
    unsigned short* lb1 = &lds_b[fl1 * 8];

    // Fragment read: row R = wm + t*16 + fm, chunk fq.
    // p = R*4 + (fq ^ ((R>>1)&3)); since wm%64==0 and t*16 contribute 0 to
    // (R>>1)&3, the swizzle term is fq ^ ((fm>>1)&3).
    const int fm = lane & 15;
    const int fq = lane >> 4;
    const int swz = fq ^ ((fm >> 1) & 3);

    const unsigned short* ra[4];
    const unsigned short* rb[4];
#pragma unroll
    for (int t = 0; t < 4; ++t) {
        const int pa = (wm + t * 16 + fm) * 4 + swz;
        const int pb = (wn + t * 16 + fm) * 4 + swz;
        ra[t] = &lds_a[pa * 8];
        rb[t] = &lds_b[pb * 8];
    }

    for (int k0 = 0; k0 < K; k0 += BK) {
        __syncthreads();  // prior iteration's LDS reads complete
        load16_g2l(ga0 + k0, la0);
        load16_g2l(ga1 + k0, la1);
        load16_g2l(gb0 + k0, lb0);
        load16_g2l(gb1 + k0, lb1);
        __syncthreads();  // staging drained

        bf16x8 av[4], bv[4];
#pragma unroll
        for (int t = 0; t < 4; ++t) av[t] = *(const bf16x8*)ra[t];
#pragma unroll
        for (int t = 0; t < 4; ++t) bv[t] = *(const bf16x8*)rb[t];
#pragma unroll
        for (int i = 0; i < 4; ++i)
#pragma unroll
            for (int j = 0; j < 4; ++j)
                acc[i][j] = __builtin_amdgcn_mfma_f32_16x16x32_bf16(
                    av[i], bv[j], acc[i][j], 0, 0, 0);
    }

    // Epilogue: C/D layout col = lane&15 (n), row = fq*4 + reg (m). Fused bias.
#pragma unroll
    for (int j = 0; j < 4; ++j) {
        const int col = n0 + wn + j * 16 + fm;
        const float bvl = bias[col];
#pragma unroll
        for (int i = 0; i < 4; ++i) {
            const int rbase = m0 + wm + i * 16 + fq * 4;
#pragma unroll
            for (int r = 0; r < 4; ++r) {
                C[(size_t)(rbase + r) * N + col] = acc[i][j][r] + bvl;
            }
        }
    }
}

// ---------------- fallback (ws too small): naive fp32 ----------------
__global__ __launch_bounds__(256) void fallback_naive(
    const float* __restrict__ in, const int* __restrict__ w,
    const float* __restrict__ scale, const float* __restrict__ zp,
    const float* __restrict__ bias, float* __restrict__ out,
    int M, int N, int K) {
    int idx = blockIdx.x * 256 + threadIdx.x;
    if (idx >= M * N) return;
    int m = idx / N, n = idx - m * N;
    const float s = scale[n], z = zp[n];
    const float* a = in + (size_t)m * K;
    const int* wr = w + (size_t)n * K;
    float acc = 0.f;
    for (int k = 0; k < K; ++k) acc += a[k] * ((float)wr[k] - z);
    out[idx] = acc * s + bias[n];
}

extern "C" void kernel_launch(void* const* d_in, const int* in_sizes, int n_in,
                              void* d_out, int out_size, void* d_ws, size_t ws_size,
                              hipStream_t stream) {
    constexpr int M = 4 * 2048;  // B*S
    constexpr int K = 4096;      // IN
    constexpr int N = 4096;      // OUT

    const float* input = (const float*)d_in[0];
    const int* w8 = (const int*)d_in[1];
    const float* scale = (const float*)d_in[2];
    const float* zp = (const float*)d_in[3];
    const float* bias = (const float*)d_in[4];
    float* out = (float*)d_out;

    const size_t need = ((size_t)M * K + (size_t)N * K) * sizeof(unsigned short);
    if (ws_size < need) {
        const int total = M * N;
        fallback_naive<<<(total + 255) / 256, 256, 0, stream>>>(
            input, w8, scale, zp, bias, out, M, N, K);
        return;
    }

    unsigned short* wsA = (unsigned short*)d_ws;   // M*K bf16
    unsigned short* wsW = wsA + (size_t)M * K;     // N*K bf16

    const int ga_blocks = (M * K) / 1024;          // 32768
    const int gw_blocks = (N * K) / 1024;          // 16384
    prep<<<ga_blocks + gw_blocks, 256, 0, stream>>>(
        input, wsA, w8, scale, zp, wsW, ga_blocks);

    dim3 grid(N / BN, M / BM);  // (32, 64) = 2048 blocks
    gemm_bf16_bt<<<grid, 256, 0, stream>>>(wsA, wsW, bias, out, M, N, K);
}